// Round 5
// baseline (2566.419 us; speedup 1.0000x reference)
//
#include <hip/hip_runtime.h>

typedef unsigned short u16;
typedef __attribute__((ext_vector_type(8))) short short8_t;
typedef __attribute__((ext_vector_type(2))) float f32x2_t;
typedef __attribute__((ext_vector_type(4))) float f32x4_t;
typedef __attribute__((ext_vector_type(16))) float f32x16_t;

#define NWG 128
#define SMEM_RECUR (82 * 1024)

// ---------------- helpers ----------------
__device__ __forceinline__ u16 f2bf(float f) {
  union { float f; unsigned u; } v; v.f = f;
  unsigned r = v.u + 0x7fffu + ((v.u >> 16) & 1u);  // RNE
  return (u16)(r >> 16);
}

typedef __attribute__((address_space(1))) const void gas_t;
typedef __attribute__((address_space(3))) void las_t;
__device__ __forceinline__ void gl16(const void* g, void* l) {
  __builtin_amdgcn_global_load_lds((gas_t*)g, (las_t*)l, 16, 0, 0);
}

// ---------------- prep (vectorized xb conversion) ----------------
__global__ void prep_kernel(const float* __restrict__ inputo, const float* __restrict__ attn,
                            const float* __restrict__ init_hx,
                            u16* __restrict__ xb, u16* __restrict__ hb, unsigned* __restrict__ flags) {
  int i = blockIdx.x * blockDim.x + threadIdx.x;
  int nthr = gridDim.x * blockDim.x;
  if (i < NWG * 16) flags[i] = 0u;
  for (int j = i; j < 32 * 1024; j += nthr) hb[j] = f2bf(init_hx[j & 1023]);
  // 8 bf16 per iteration: rows of 2048 = [inputo row | attn row], 1024%8==0 so the
  // source branch is uniform within each 8-group and float4 loads stay 16B-aligned.
  for (long j8 = i; j8 < (long)8192 * 256; j8 += nthr) {
    long r = j8 >> 8; int k = (int)(j8 & 255) << 3;
    const float* src = (k < 1024) ? (inputo + (r << 10) + k) : (attn + (r << 10) + (k - 1024));
    f32x4_t a = *(const f32x4_t*)(src);
    f32x4_t b = *(const f32x4_t*)(src + 4);
    union { unsigned u[4]; } o;
    o.u[0] = (unsigned)f2bf(a[0]) | ((unsigned)f2bf(a[1]) << 16);
    o.u[1] = (unsigned)f2bf(a[2]) | ((unsigned)f2bf(a[3]) << 16);
    o.u[2] = (unsigned)f2bf(b[0]) | ((unsigned)f2bf(b[1]) << 16);
    o.u[3] = (unsigned)f2bf(b[2]) | ((unsigned)f2bf(b[3]) << 16);
    *(uint4*)(xb + (r << 11) + k) = make_uint4(o.u[0], o.u[1], o.u[2], o.u[3]);
  }
}

// ---------------- W transpose->bf16 ----------------
__global__ void transw_kernel(const float* __restrict__ W, u16* __restrict__ WbT) {
  __shared__ float tile[64][65];
  int kt = blockIdx.x;
  int nt = blockIdx.y;
  int t = threadIdx.x;
  int r = t >> 6, c = t & 63;
#pragma unroll
  for (int p = 0; p < 16; p++) {
    int k = (kt << 6) + (p << 2) + r;
    tile[(p << 2) + r][c] = W[(long)k * 4096 + (nt << 6) + c];
  }
  __syncthreads();
#pragma unroll
  for (int p = 0; p < 16; p++) {
    int n = (nt << 6) + (p << 2) + r;
    WbT[(long)n * 3072 + (kt << 6) + c] = f2bf(tile[c][(p << 2) + r]);
  }
}

// ---------------- Gx GEMM (XCD-swizzled 1D grid) ----------------
__global__ __launch_bounds__(256) void gemmx_kernel(const u16* __restrict__ xb, const u16* __restrict__ WbT,
                                                    const float* __restrict__ bias, float* __restrict__ Gx) {
  __shared__ __align__(16) char sA[128 * 64 * 2];
  __shared__ __align__(16) char sB[128 * 64 * 2];
  int tid = threadIdx.x, lane = tid & 63, wave = tid >> 6;
  // 2048 blocks, 2048 % 8 == 0: bijective XCD swizzle; each XCD owns 256
  // consecutive tiles = 8 m-rows x 32 n (shares A panels within an XCD L2).
  int bid = blockIdx.x;
  int swz = (bid & 7) * 256 + (bid >> 3);
  int m0 = (swz >> 5) << 7, n0 = (swz & 31) << 7;
  int mi2 = wave >> 1, ni2 = wave & 1;
  const char* xbb = (const char*)xb;
  const char* wbb = (const char*)WbT;
  f32x4_t acc[4][4];
#pragma unroll
  for (int i = 0; i < 4; i++)
#pragma unroll
    for (int j = 0; j < 4; j++)
      acc[i][j] = (f32x4_t){0.f, 0.f, 0.f, 0.f};

  for (int kt = 0; kt < 32; kt++) {
    int k0b = kt << 7;
#pragma unroll
    for (int cc = 0; cc < 4; cc++) {
      int L = (cc << 12) + (tid << 4);
      int row = L >> 7, colb = L & 127;
      gl16(xbb + (long)(m0 + row) * 4096 + k0b + (colb ^ ((row & 7) << 4)),
           sA + (cc << 12) + (wave << 10));
      gl16(wbb + (long)(n0 + row) * 6144 + k0b + (colb ^ ((row & 7) << 4)),
           sB + (cc << 12) + (wave << 10));
    }
    __syncthreads();
#pragma unroll
    for (int ks = 0; ks < 2; ks++) {
      short8_t af[4], bf[4];
#pragma unroll
      for (int i = 0; i < 4; i++) {
        int m = (mi2 << 6) + (i << 4) + (lane & 15);
        int kb = (ks << 6) + ((lane >> 4) << 4);
        af[i] = *(const short8_t*)(sA + (m << 7) + (kb ^ ((m & 7) << 4)));
        int n = (ni2 << 6) + (i << 4) + (lane & 15);
        bf[i] = *(const short8_t*)(sB + (n << 7) + (kb ^ ((n & 7) << 4)));
      }
#pragma unroll
      for (int i = 0; i < 4; i++)
#pragma unroll
        for (int j = 0; j < 4; j++)
          acc[i][j] = __builtin_amdgcn_mfma_f32_16x16x32_bf16(af[i], bf[j], acc[i][j], 0, 0, 0);
    }
    __syncthreads();
  }
#pragma unroll
  for (int j = 0; j < 4; j++) {
    int col = n0 + (ni2 << 6) + (j << 4) + (lane & 15);
    float bval = bias[col];
#pragma unroll
    for (int i = 0; i < 4; i++) {
      int rb = m0 + (mi2 << 6) + (i << 4) + ((lane >> 4) << 2);
#pragma unroll
      for (int r = 0; r < 4; r++)
        Gx[(long)(rb + r) * 4096 + col] = acc[i][j][r] + bval;
    }
  }
}

// ---------------- poll: early-exit masked + sleep ----------------
__device__ __forceinline__ void poll_flags(unsigned* flags, int tid, unsigned ep) {
  if (tid < NWG) {
    unsigned* fp = &flags[tid << 4];
    bool done = __hip_atomic_load(fp, __ATOMIC_RELAXED, __HIP_MEMORY_SCOPE_AGENT) >= ep;
    while (!__all(done)) {
      __builtin_amdgcn_s_sleep(1);
      if (!done)
        done = __hip_atomic_load(fp, __ATOMIC_RELAXED, __HIP_MEMORY_SCOPE_AGENT) >= ep;
    }
  }
  __syncthreads();
}

// ---------------- persistent recurrent kernel ----------------
__global__ __launch_bounds__(256, 1) void recur_kernel(
    const float* __restrict__ inputo, const u16* __restrict__ WbT, const float* __restrict__ Gx,
    const float* __restrict__ ln_g, const float* __restrict__ ln_b, const float* __restrict__ init_cx,
    u16* __restrict__ hb, unsigned long long* __restrict__ partials, unsigned* __restrict__ flags,
    float* __restrict__ dump, float* __restrict__ out) {
  extern __shared__ __align__(16) char smem[];
  char* Wh = smem;
  float* accb = (float*)(smem + 65536);
  int wg = blockIdx.x, tid = threadIdx.x, lane = tid & 63, wave = tid >> 6;
  int jb = wg << 3;
  int gq = tid & 7;
  int b = tid >> 3;
  int gj = jb + gq;
  float lng0 = ln_g[gj], lng1 = ln_g[1024 + gj], lng2 = ln_g[2048 + gj], lng3 = ln_g[3072 + gj];
  float lnb0 = ln_b[gj], lnb1 = ln_b[1024 + gj], lnb2 = ln_b[2048 + gj], lnb3 = ln_b[3072 + gj];
  float creg = init_cx[gj];

  const char* wbb = (const char*)WbT;
  const char* hbb = (const char*)hb;
  unsigned* hb32 = (unsigned*)hb;

  // stage W_h slice once (swizzled image)
#pragma unroll
  for (int cc = 0; cc < 16; cc++) {
    int L = (cc << 12) + (tid << 4);
    int row = L >> 11, colb = L & 2047;
    int n = ((row >> 3) << 10) + jb + (row & 7);
    gl16(wbb + (long)n * 6144 + 4096 + (colb ^ ((row & 15) << 4)),
         Wh + (cc << 12) + (wave << 10));
  }
  asm volatile("s_waitcnt vmcnt(0)" ::: "memory");
  __syncthreads();

  int m = lane & 31, g2 = lane >> 5;
  int cs = gq << 2, gate = cs >> 3, joff = cs & 7;
  long orow = (long)b << 8;
  float out_prev = 0.f;

#pragma unroll 1
  for (int t = 0; t < 256; t++) {
    // ---- issue: out store (prev step), 16 h loads, Gx, inputo — exact vmcnt counts
    {
      float* outp = (t > 0) ? (out + ((orow + t - 1) << 10) + gj) : (dump + tid);
      asm volatile("global_store_dword %0, %1, off" :: "v"(outp), "v"(out_prev) : "memory");
    }
    short8_t av[16];
#pragma unroll
    for (int ks = 0; ks < 16; ks++) {
      int kb = (wave << 9) + (ks << 5) + (g2 << 4);
      const char* p = hbb + (m << 11) + kb;
      asm volatile("global_load_dwordx4 %0, %1, off sc0 sc1" : "=v"(av[ks]) : "v"(p));
    }
    f32x4_t gxv;
    {
      const float* gp = Gx + (((orow + t) << 12)) + (gate << 10) + jb + joff;
      asm volatile("global_load_dwordx4 %0, %1, off" : "=v"(gxv) : "v"(gp));
    }
    float inp;
    {
      const float* ip = inputo + ((orow + t) << 10) + gj;
      asm volatile("global_load_dword %0, %1, off" : "=v"(inp) : "v"(ip));
    }
    // wait: out store + h loads retired; Gx, inp still in flight
    asm volatile("s_waitcnt vmcnt(2)"
                 : "+v"(av[0]), "+v"(av[1]), "+v"(av[2]), "+v"(av[3]),
                   "+v"(av[4]), "+v"(av[5]), "+v"(av[6]), "+v"(av[7]),
                   "+v"(av[8]), "+v"(av[9]), "+v"(av[10]), "+v"(av[11]),
                   "+v"(av[12]), "+v"(av[13]), "+v"(av[14]), "+v"(av[15])
                 :: "memory");
    __builtin_amdgcn_sched_barrier(0);

    // ---- GEMM, dual accumulator chains
    f32x16_t acc0 = {0.f,0.f,0.f,0.f,0.f,0.f,0.f,0.f,0.f,0.f,0.f,0.f,0.f,0.f,0.f,0.f};
    f32x16_t acc1 = {0.f,0.f,0.f,0.f,0.f,0.f,0.f,0.f,0.f,0.f,0.f,0.f,0.f,0.f,0.f,0.f};
#pragma unroll
    for (int ks = 0; ks < 8; ks++) {
      int kb0 = (wave << 9) + ((2 * ks) << 5) + (g2 << 4);
      int kb1 = (wave << 9) + ((2 * ks + 1) << 5) + (g2 << 4);
      short8_t bv0 = *(const short8_t*)(Wh + (m << 11) + (kb0 ^ ((m & 15) << 4)));
      short8_t bv1 = *(const short8_t*)(Wh + (m << 11) + (kb1 ^ ((m & 15) << 4)));
      acc0 = __builtin_amdgcn_mfma_f32_32x32x16_bf16(av[2 * ks], bv0, acc0, 0, 0, 0);
      acc1 = __builtin_amdgcn_mfma_f32_32x32x16_bf16(av[2 * ks + 1], bv1, acc1, 0, 0, 0);
    }
#pragma unroll
    for (int r = 0; r < 16; r++) acc0[r] += acc1[r];
    // C layout 32x32: col = lane&31, row = (r&3) + 8*(r>>2) + 4*(lane>>5)
#pragma unroll
    for (int r = 0; r < 16; r++) {
      int row = (r & 3) + ((r >> 2) << 3) + (g2 << 2);
      accb[(wave << 10) + (row << 5) + m] = acc0[r];
    }
    __syncthreads();

    // ---- reduce 4 K-partials + Gx (vectorized), LN stats partials
    int e0 = (b << 5) + cs;
    f32x4_t p0 = *(const f32x4_t*)(accb + e0);
    f32x4_t p1 = *(const f32x4_t*)(accb + 1024 + e0);
    f32x4_t p2 = *(const f32x4_t*)(accb + 2048 + e0);
    f32x4_t p3 = *(const f32x4_t*)(accb + 3072 + e0);
    asm volatile("s_waitcnt vmcnt(1)" : "+v"(gxv) :: "memory");
    __builtin_amdgcn_sched_barrier(0);
    f32x4_t gv;
#pragma unroll
    for (int u = 0; u < 4; u++) gv[u] = p0[u] + p1[u] + p2[u] + p3[u] + gxv[u];
    *(f32x4_t*)(accb + e0) = gv;
    float s = gv[0] + gv[1] + gv[2] + gv[3];
    float ss = gv[0]*gv[0] + gv[1]*gv[1] + gv[2]*gv[2] + gv[3]*gv[3];
#pragma unroll
    for (int mk = 1; mk < 8; mk <<= 1) { s += __shfl_xor(s, mk, 64); ss += __shfl_xor(ss, mk, 64); }
    if (gq == 0) {
      union { unsigned long long u; float2 f; } pv; pv.f = make_float2(s, ss);
      __hip_atomic_store(&partials[(b << 7) + wg], pv.u, __ATOMIC_RELAXED, __HIP_MEMORY_SCOPE_AGENT);
    }

    // ---- barrier 1: partials ready
    unsigned ep1 = (unsigned)(2 * t + 1);
    asm volatile("s_waitcnt vmcnt(0)" : "+v"(inp) :: "memory");
    __syncthreads();
    if (tid == 0) __hip_atomic_store(&flags[wg << 4], ep1, __ATOMIC_RELAXED, __HIP_MEMORY_SCOPE_AGENT);
    poll_flags(flags, tid, ep1);

    // ---- LN stats finalize
    float s2 = 0.f, ss2 = 0.f;
    {
      const unsigned long long* pp = partials + (b << 7) + (gq << 4);
#pragma unroll
      for (int i2 = 0; i2 < 16; i2++) {
        union { unsigned long long u; float2 f; } pv;
        pv.u = __hip_atomic_load(&pp[i2], __ATOMIC_RELAXED, __HIP_MEMORY_SCOPE_AGENT);
        s2 += pv.f.x; ss2 += pv.f.y;
      }
#pragma unroll
      for (int mk = 1; mk < 8; mk <<= 1) { s2 += __shfl_xor(s2, mk, 64); ss2 += __shfl_xor(ss2, mk, 64); }
    }
    float mean = s2 * (1.f / 4096.f);
    float var = ss2 * (1.f / 4096.f) - mean * mean;
    float rstd = rsqrtf(var + 1e-5f);

    // ---- gates + cell update
    {
      float g0 = accb[(b << 5) + gq];
      float g1 = accb[(b << 5) + 8 + gq];
      float g2v = accb[(b << 5) + 16 + gq];
      float g3 = accb[(b << 5) + 24 + gq];
      g0 = (g0 - mean) * rstd * lng0 + lnb0;
      g1 = (g1 - mean) * rstd * lng1 + lnb1;
      g2v = (g2v - mean) * rstd * lng2 + lnb2;
      g3 = (g3 - mean) * rstd * lng3 + lnb3;
      float iv = 1.f / (1.f + __expf(-g0));
      float fv = 1.f / (1.f + __expf(-g1));
      float ov = 1.f / (1.f + __expf(-g2v));
      float e2 = __expf(2.f * g3);
      float hv = (e2 - 1.f) / (e2 + 1.f);
      creg = fv * creg + iv * hv;
      float h = ov * creg;
      out_prev = h + inp;
      float hn = __shfl_down(h, 1, 64);
      if ((gq & 1) == 0) {
        unsigned pk = (unsigned)f2bf(h) | ((unsigned)f2bf(hn) << 16);
        __hip_atomic_store(&hb32[(b << 9) + (gj >> 1)], pk, __ATOMIC_RELAXED, __HIP_MEMORY_SCOPE_AGENT);
      }
    }

    // ---- barrier 2: h ready
    unsigned ep2 = ep1 + 1;
    asm volatile("s_waitcnt vmcnt(0)" ::: "memory");
    __syncthreads();
    if (tid == 0) __hip_atomic_store(&flags[wg << 4], ep2, __ATOMIC_RELAXED, __HIP_MEMORY_SCOPE_AGENT);
    poll_flags(flags, tid, ep2);
  }
  out[((orow + 255) << 10) + gj] = out_prev;
}

__global__ void sentinel_kernel(float* out) { out[0] = 1.2345678e7f; }

extern "C" void kernel_launch(void* const* d_in, const int* in_sizes, int n_in,
                              void* d_out, int out_size, void* d_ws, size_t ws_size,
                              hipStream_t stream) {
  (void)in_sizes; (void)n_in; (void)out_size;
  const float* inputo  = (const float*)d_in[0];
  const float* attn    = (const float*)d_in[1];
  const float* W       = (const float*)d_in[2];
  const float* bias    = (const float*)d_in[3];
  const float* ln_g    = (const float*)d_in[4];
  const float* ln_b    = (const float*)d_in[5];
  const float* init_hx = (const float*)d_in[6];
  const float* init_cx = (const float*)d_in[7];
  float* out = (float*)d_out;
  char* ws = (char*)d_ws;

  const size_t OFF_XB   = 0;          // 8192*2048*2  = 33554432
  const size_t OFF_WBT  = 33554432;   // 4096*3072*2  = 25165824
  const size_t OFF_GX   = 58720256;   // 8192*4096*4  = 134217728
  const size_t OFF_HB   = 192937984;  // 32*1024*2    = 65536
  const size_t OFF_PART = 193003520;  // 32*128*8     = 32768
  const size_t OFF_FLAG = 193036288;  // 128*16*4     = 8192
  const size_t OFF_DUMP = 193044480;  // 1024 bytes
  const size_t NEED     = 193045504;

  if (ws_size < NEED) { sentinel_kernel<<<1, 1, 0, stream>>>(out); return; }

  u16* xb   = (u16*)(ws + OFF_XB);
  u16* WbT  = (u16*)(ws + OFF_WBT);
  float* Gx = (float*)(ws + OFF_GX);
  u16* hb   = (u16*)(ws + OFF_HB);
  unsigned long long* partials = (unsigned long long*)(ws + OFF_PART);
  unsigned* flags = (unsigned*)(ws + OFF_FLAG);
  float* dump = (float*)(ws + OFF_DUMP);

  prep_kernel<<<2048, 256, 0, stream>>>(inputo, attn, init_hx, xb, hb, flags);
  transw_kernel<<<dim3(48, 64), 256, 0, stream>>>(W, WbT);
  gemmx_kernel<<<2048, 256, 0, stream>>>(xb, WbT, bias, Gx);

  hipFuncSetAttribute((const void*)recur_kernel, hipFuncAttributeMaxDynamicSharedMemorySize, SMEM_RECUR);
  void* kargs[] = {(void*)&inputo, (void*)&WbT, (void*)&Gx, (void*)&ln_g, (void*)&ln_b,
                   (void*)&init_cx, (void*)&hb, (void*)&partials, (void*)&flags, (void*)&dump,
                   (void*)&out};
  hipLaunchCooperativeKernel((void*)recur_kernel, dim3(NWG), dim3(256), kargs, SMEM_RECUR, stream);
}